// Round 6
// baseline (320.033 us; speedup 1.0000x reference)
//
#include <hip/hip_runtime.h>
#include <hip/hip_bf16.h>

typedef _Float16 f16x8 __attribute__((ext_vector_type(8)));
typedef float f32x4 __attribute__((ext_vector_type(4)));

#define MFMA16(a, b, c) __builtin_amdgcn_mfma_f32_16x16x32_f16(a, b, c, 0, 0, 0)

__device__ __forceinline__ void load_lds16(const void* g, void* l) {
  __builtin_amdgcn_global_load_lds(
      (__attribute__((address_space(1))) void*)g,
      (__attribute__((address_space(3))) void*)l, 16, 0, 0);
}

// ---------------- f32 -> f16 convert (8 elems / thread / iter) ----------------
__global__ __launch_bounds__(256) void k_cvt16(const float* __restrict__ in,
                                               _Float16* __restrict__ out, int n8) {
  int stride = gridDim.x * blockDim.x;
  for (int i = blockIdx.x * blockDim.x + threadIdx.x; i < n8; i += stride) {
    const float4* p = (const float4*)(in + (size_t)i * 8);
    float4 a = p[0], b = p[1];
    f16x8 v = {(_Float16)a.x, (_Float16)a.y, (_Float16)a.z, (_Float16)a.w,
               (_Float16)b.x, (_Float16)b.y, (_Float16)b.z, (_Float16)b.w};
    *(f16x8*)(out + (size_t)i * 8) = v;
  }
}

// ---------- transpose + convert: in[K][N] f32 -> out[N][K] f16, 64x64 tiles ----------
__global__ __launch_bounds__(256) void k_transpose(const float* __restrict__ in,
                                                   _Float16* __restrict__ out, int K, int N) {
  __shared__ float tile[64][65];
  int k0 = blockIdx.y * 64, n0 = blockIdx.x * 64;
  int t = threadIdx.x;
  {
    int nn = t & 63, kb = t >> 6;
#pragma unroll
    for (int i = 0; i < 16; ++i) {
      int kk = kb + i * 4;
      tile[kk][nn] = in[(size_t)(k0 + kk) * N + n0 + nn];
    }
  }
  __syncthreads();
  {
    int kk = t & 63, nb = t >> 6;
#pragma unroll
    for (int i = 0; i < 16; ++i) {
      int nn = nb + i * 4;
      out[(size_t)(n0 + nn) * K + k0 + kk] = (_Float16)tile[kk][nn];
    }
  }
}

// ---------------- K/V projection: ctxh[616][768] @ W^T -> heads ----------------
__global__ __launch_bounds__(64) void k_kvproj(const _Float16* __restrict__ ctxh,
                                               const _Float16* __restrict__ Wkt,
                                               const _Float16* __restrict__ Wvt,
                                               _Float16* __restrict__ Kg,
                                               _Float16* __restrict__ Vtg) {
  int mt = blockIdx.x, nt = blockIdx.y;
  int lane = threadIdx.x;
  int l15 = lane & 15, lhi = lane >> 4;
  int arow = mt * 16 + l15;
  if (arow > 615) arow = 615;  // clamp; masked at write
  const _Float16* ap = ctxh + (size_t)arow * 768 + lhi * 8;
  const _Float16* kp = Wkt + (size_t)(nt * 16 + l15) * 768 + lhi * 8;
  const _Float16* vp = Wvt + (size_t)(nt * 16 + l15) * 768 + lhi * 8;
  f32x4 ak = {0.f, 0.f, 0.f, 0.f}, av = {0.f, 0.f, 0.f, 0.f};
#pragma unroll 4
  for (int ks = 0; ks < 24; ++ks) {
    f16x8 a = *(const f16x8*)(ap + ks * 32);
    f16x8 bk = *(const f16x8*)(kp + ks * 32);
    f16x8 bv = *(const f16x8*)(vp + ks * 32);
    ak = MFMA16(a, bk, ak);
    av = MFMA16(a, bv, av);
  }
  int n = nt * 16 + l15, h = n >> 6, d = n & 63;
#pragma unroll
  for (int j = 0; j < 4; ++j) {
    int gm = mt * 16 + lhi * 4 + j;
    if (gm < 616) {
      int b = gm / 77, m = gm - b * 77;
      Kg[((size_t)(b * 16 + h) * 77 + m) * 64 + d] = (_Float16)ak[j];
      Vtg[((size_t)(b * 16 + h) * 64 + d) * 128 + m] = (_Float16)av[j];
    }
  }
}

// ---------------- attention: one block = one (b,h) x 64 query rows ----------------
__global__ __launch_bounds__(256) void k_attn(const _Float16* __restrict__ Qh,
                                              const _Float16* __restrict__ Kg,
                                              const _Float16* __restrict__ Vtg,
                                              _Float16* __restrict__ Out) {
  __shared__ __align__(16) char Kl[80 * 128];
  __shared__ __align__(16) char Vl[64 * 256];
  __shared__ __align__(16) char Pl[4 * 16 * 256];
  int bh = blockIdx.y, b = bh >> 4, h = bh & 15;
  int t = threadIdx.x, wid = t >> 6, lane = t & 63;
  int l15 = lane & 15, lhi = lane >> 4;

  const _Float16* Kgp = Kg + (size_t)bh * (77 * 64);
  const _Float16* Vgp = Vtg + (size_t)bh * (64 * 128);

  for (int idx = t; idx < 640; idx += 256) {
    int m = idx >> 3, c = (idx & 7) * 8;
    f16x8 v = {};
    if (m < 77) v = *(const f16x8*)(Kgp + m * 64 + c);
    *(f16x8*)(Kl + ((m * 128 + c * 2) ^ ((m & 7) << 4))) = v;
  }
  for (int idx = t; idx < 1024; idx += 256) {
    int d = idx >> 4, c = (idx & 15) * 8;
    f16x8 v = *(const f16x8*)(Vgp + d * 128 + c);
    *(f16x8*)(Vl + ((d * 256 + c * 2) ^ ((d & 7) << 4))) = v;
  }
  char* myP = Pl + wid * 4096;
#pragma unroll
  for (int i = 0; i < 4; ++i) *(f16x8*)(myP + lane * 64 + i * 16) = f16x8{};
  __syncthreads();

  int qrow = b * 4096 + blockIdx.x * 64 + wid * 16 + l15;
  const _Float16* qp = Qh + (size_t)qrow * 1024 + h * 64 + lhi * 8;
  f16x8 q0 = *(const f16x8*)qp;
  f16x8 q1 = *(const f16x8*)(qp + 32);

  float e[5][4];
  float mx[4] = {-1e30f, -1e30f, -1e30f, -1e30f};
#pragma unroll
  for (int ct = 0; ct < 5; ++ct) {
    int m = ct * 16 + l15;
    int d0b = lhi * 16;
    f16x8 k0 = *(const f16x8*)(Kl + ((m * 128 + d0b) ^ ((m & 7) << 4)));
    f16x8 k1 = *(const f16x8*)(Kl + ((m * 128 + 64 + d0b) ^ ((m & 7) << 4)));
    f32x4 acc = {0.f, 0.f, 0.f, 0.f};
    acc = MFMA16(q0, k0, acc);
    acc = MFMA16(q1, k1, acc);
    bool valid = m < 77;
#pragma unroll
    for (int j = 0; j < 4; ++j) {
      float v = valid ? acc[j] * 0.125f : -1e30f;
      e[ct][j] = v;
      mx[j] = fmaxf(mx[j], v);
    }
  }
#pragma unroll
  for (int off = 1; off < 16; off <<= 1)
#pragma unroll
    for (int j = 0; j < 4; ++j) mx[j] = fmaxf(mx[j], __shfl_xor(mx[j], off, 64));
  float sm[4] = {0.f, 0.f, 0.f, 0.f};
#pragma unroll
  for (int ct = 0; ct < 5; ++ct)
#pragma unroll
    for (int j = 0; j < 4; ++j) {
      float ev = __expf(e[ct][j] - mx[j]);
      e[ct][j] = ev;
      sm[j] += ev;
    }
#pragma unroll
  for (int off = 1; off < 16; off <<= 1)
#pragma unroll
    for (int j = 0; j < 4; ++j) sm[j] += __shfl_xor(sm[j], off, 64);
  float rs[4];
#pragma unroll
  for (int j = 0; j < 4; ++j) rs[j] = 1.0f / sm[j];

#pragma unroll
  for (int ct = 0; ct < 5; ++ct) {
    int m = ct * 16 + l15;
#pragma unroll
    for (int j = 0; j < 4; ++j) {
      int r = lhi * 4 + j;
      *(_Float16*)(myP + ((r * 256 + m * 2) ^ ((r & 7) << 4))) =
          (_Float16)(e[ct][j] * rs[j]);
    }
  }

  f32x4 o[4] = {{0.f,0.f,0.f,0.f},{0.f,0.f,0.f,0.f},{0.f,0.f,0.f,0.f},{0.f,0.f,0.f,0.f}};
#pragma unroll
  for (int ks = 0; ks < 3; ++ks) {
    int m0b = ks * 64 + lhi * 16;
    f16x8 pa = *(const f16x8*)(myP + ((l15 * 256 + m0b) ^ ((l15 & 7) << 4)));
#pragma unroll
    for (int dt = 0; dt < 4; ++dt) {
      int d = dt * 16 + l15;
      f16x8 vb = *(const f16x8*)(Vl + ((d * 256 + m0b) ^ ((d & 7) << 4)));
      o[dt] = MFMA16(pa, vb, o[dt]);
    }
  }
  _Float16* op = Out + (size_t)(b * 4096 + blockIdx.x * 64 + wid * 16) * 1024 + h * 64;
#pragma unroll
  for (int dt = 0; dt < 4; ++dt)
#pragma unroll
    for (int j = 0; j < 4; ++j) {
      int r = lhi * 4 + j;
      op[(size_t)r * 1024 + dt * 16 + l15] = (_Float16)o[dt][j];
    }
}

// ============ 128x256 GEMM, 3-buffer ring, 1 barrier + 1 counted vmcnt per K-tile ===
// A [M][K] f16, Bt [N][K] f16. BK=64, 512 thr = 8 waves (2M x 4N), per-wave 64x64.
// LDS ring: 3 bufs x (A 16KB + B 32KB) = 144KB. Tile t reads buf[t%3]; gloads for
// tile t+2 target buf[(t+2)%3] == buf[(t-1)%3] (dead: its reads finished before the
// barrier of tile t). Per tile: vmcnt(6) retires tile t's 6 gloads (issued at t-2),
// then s_barrier publishes ALL waves' gloads; then issue 6 gloads for t+2; then
// 16 ds_read_b128 + 32 MFMA16 with NO further sync (waves slip; LDS overlaps MFMA).
// Read swizzle: 16B-chunk ^= (row&7) both sides (conflict-free 8-chunk spread).
template <int FINAL>
__global__ __launch_bounds__(512, 2) void k_gemm4(const _Float16* __restrict__ A,
                                                  const _Float16* __restrict__ Bt,
                                                  void* __restrict__ Cout,
                                                  const float* __restrict__ bias,
                                                  int M, int N, int K) {
  __shared__ __align__(16) char lds[147456];
  const int t = threadIdx.x, wid = t >> 6, lane = t & 63;
  const int wr = wid >> 2, wc = wid & 3;  // 2M x 4N wave grid
  const int l15 = lane & 15, lhi = lane >> 4;

  // T1: bijective XCD swizzle (nwg % 8 == 0); tn fastest -> each XCD gets
  // contiguous tm panels (A-panel L2 reuse across the 4 tn blocks).
  int nwg = gridDim.x, bid = blockIdx.x;
  int wg = ((nwg & 7) == 0) ? ((bid & 7) * (nwg >> 3) + (bid >> 3)) : bid;
  const int nTN = N >> 8;
  const int tm = wg / nTN, tn = wg % nTN;

  const _Float16* Ag = A + (size_t)tm * 128 * K;
  const _Float16* Bg = Bt + (size_t)tn * 256 * K;
  // staging source: row = wid*8 + (lane>>3) (+slice), chunk pre-swizzled by row&7
  const size_t stg = (size_t)(wid * 8 + (lane >> 3)) * K +
                     (size_t)(((lane & 7) ^ ((lane >> 3) & 7)) * 8);
  const int dstg = wid * 1024;  // linear wave dest (HW adds lane*16)

  // read swizzle: byte chunk = (kk*4 + lhi) ^ (l15 & 7); kk toggle = byte ^ 64
  const int cA = ((lhi ^ (l15 & 7)) << 4);

  f32x4 acc[4][4];
#pragma unroll
  for (int i = 0; i < 4; ++i)
#pragma unroll
    for (int j = 0; j < 4; ++j) acc[i][j] = f32x4{0.f, 0.f, 0.f, 0.f};

#define STG_TILE(T, BUF)                                                          \
  {                                                                               \
    const size_t co = (size_t)(T) * 64;                                           \
    char* d = lds + (BUF) * 49152 + dstg;                                         \
    load_lds16(Ag + stg + co, d);                                                 \
    load_lds16(Ag + stg + (size_t)64 * K + co, d + 64 * 128);                     \
    load_lds16(Bg + stg + co, d + 16384);                                         \
    load_lds16(Bg + stg + (size_t)64 * K + co, d + 16384 + 64 * 128);             \
    load_lds16(Bg + stg + (size_t)128 * K + co, d + 16384 + 128 * 128);           \
    load_lds16(Bg + stg + (size_t)192 * K + co, d + 16384 + 192 * 128);           \
  }
#define VM6 asm volatile("s_waitcnt vmcnt(6)" ::: "memory")
#define VM0 asm volatile("s_waitcnt vmcnt(0)" ::: "memory")
#define BAR __builtin_amdgcn_s_barrier()

  const int nT = K >> 6;  // 16 for K=1024 (needs nT >= 3)

  // prologue: stage tile 0 -> buf0, tile 1 -> buf1 (12 gloads in flight / wave)
  STG_TILE(0, 0);
  STG_TILE(1, 1);

  int bufR = 0;
  for (int tt = 0; tt < nT; ++tt) {
    if (tt == nT - 1) { VM0; } else { VM6; }  // retire tile tt's 6 gloads
    BAR;                                      // publish; all waves past tile tt-1 reads
    if (tt < nT - 2) {
      int bufS = bufR + 2; if (bufS >= 3) bufS -= 3;
      STG_TILE(tt + 2, bufS);                 // into dead buffer; 12 in flight again
    }
    // ---- compute tile tt from buf[bufR]: 16 ds_read_b128 + 32 MFMA, no sync
    const char* pA = lds + bufR * 49152 + (wr * 64 + l15) * 128 + cA;
    const char* pB = lds + bufR * 49152 + 16384 + (wc * 64 + l15) * 128 + cA;
    f16x8 a0[4], a1[4], b0[4], b1[4];
#pragma unroll
    for (int mf = 0; mf < 4; ++mf) {
      a0[mf] = *(const f16x8*)(pA + mf * 2048);
      a1[mf] = *(const f16x8*)((const char*)((size_t)(pA + mf * 2048) ^ 64));
    }
#pragma unroll
    for (int nf = 0; nf < 4; ++nf) {
      b0[nf] = *(const f16x8*)(pB + nf * 2048);
      b1[nf] = *(const f16x8*)((const char*)((size_t)(pB + nf * 2048) ^ 64));
    }
    __builtin_amdgcn_s_setprio(1);
#pragma unroll
    for (int mf = 0; mf < 4; ++mf)
#pragma unroll
      for (int nf = 0; nf < 4; ++nf) {
        acc[mf][nf] = MFMA16(a0[mf], b0[nf], acc[mf][nf]);
        acc[mf][nf] = MFMA16(a1[mf], b1[nf], acc[mf][nf]);
      }
    __builtin_amdgcn_s_setprio(0);
    bufR = (bufR == 2) ? 0 : bufR + 1;
  }

  // ---- C write: 16x16 C-layout col = l15, row = lhi*4 + reg (verified m89)
  const long rbase = (long)tm * 128 + wr * 64;
  const int cbase = tn * 256 + wc * 64;
#pragma unroll
  for (int mf = 0; mf < 4; ++mf)
#pragma unroll
    for (int nf = 0; nf < 4; ++nf) {
      int c = cbase + nf * 16 + l15;
      float bv = FINAL ? bias[c] : 0.f;
#pragma unroll
      for (int j = 0; j < 4; ++j) {
        long r = rbase + mf * 16 + lhi * 4 + j;
        float v = acc[mf][nf][j];
        if (FINAL) ((float*)Cout)[r * N + c] = v + bv;
        else ((_Float16*)Cout)[r * N + c] = (_Float16)v;
      }
    }
#undef STG_TILE
#undef VM6
#undef VM0
#undef BAR
}

extern "C" void kernel_launch(void* const* d_in, const int* in_sizes, int n_in,
                              void* d_out, int out_size, void* d_ws, size_t ws_size,
                              hipStream_t stream) {
  const float* x   = (const float*)d_in[0];
  const float* ctx = (const float*)d_in[1];
  const float* Wq  = (const float*)d_in[2];
  const float* Wk  = (const float*)d_in[3];
  const float* Wv  = (const float*)d_in[4];
  const float* Wo  = (const float*)d_in[5];
  const float* bo  = (const float*)d_in[6];

  char* ws = (char*)d_ws;
  _Float16* xh   = (_Float16*)(ws + 0);           // [32768][1024] x-f16; later attnOut
  _Float16* Wqt  = (_Float16*)(ws + 67108864);    // [1024][1024]
  _Float16* Wkt  = (_Float16*)(ws + 69206016);    // [1024][768]
  _Float16* Wvt  = (_Float16*)(ws + 70778880);    // [1024][768]
  _Float16* Wot  = (_Float16*)(ws + 72351744);    // [1024][1024]
  _Float16* ctxh = (_Float16*)(ws + 74448896);    // [616][768]
  _Float16* Kg   = (_Float16*)(ws + 75395072);    // [128][77][64]
  _Float16* Vtg  = (_Float16*)(ws + 76656640);    // [128][64][128]
  _Float16* Qh   = (_Float16*)d_out;              // [32768][1024] f16 scratch in d_out

  k_cvt16<<<4096, 256, 0, stream>>>(x, xh, 33554432 / 8);
  k_cvt16<<<231, 256, 0, stream>>>(ctx, ctxh, 473088 / 8);
  k_transpose<<<dim3(16, 16), 256, 0, stream>>>(Wq, Wqt, 1024, 1024);
  k_transpose<<<dim3(16, 12), 256, 0, stream>>>(Wk, Wkt, 768, 1024);
  k_transpose<<<dim3(16, 12), 256, 0, stream>>>(Wv, Wvt, 768, 1024);
  k_transpose<<<dim3(16, 16), 256, 0, stream>>>(Wo, Wot, 1024, 1024);
  hipMemsetAsync(Vtg, 0, 2097152, stream);
  k_kvproj<<<dim3(39, 64), 64, 0, stream>>>(ctxh, Wkt, Wvt, Kg, Vtg);
  // GEMM1: Q projection -> d_out (f16 scratch); grid = 256*4 = 1024 (%8==0)
  k_gemm4<0><<<dim3(1024), dim3(512), 0, stream>>>(xh, Wqt, (void*)Qh, nullptr, 32768, 1024, 1024);
  // attention: reads Qh (d_out), writes attnOut -> xh
  k_attn<<<dim3(64, 128), 256, 0, stream>>>(Qh, Kg, Vtg, xh);
  // GEMM2: O projection + bias -> d_out (f32)
  k_gemm4<1><<<dim3(1024), dim3(512), 0, stream>>>(xh, Wot, d_out, bo, 32768, 1024, 1024);
}